// Round 11
// baseline (1506.601 us; speedup 1.0000x reference)
//
#include <hip/hip_runtime.h>
#include <hip/hip_bf16.h>
#include <stdint.h>

// Problem constants
#define E_TOTAL 800000
#define NNODES  50000
#define NGRAPHS 64
#define NPRED   8
#define MPAD    50048          // rows padded to 64 (782*64)
#define EBLK    12500          // 800000/64 edge blocks
#define NBLK    782            // 50048/64 node blocks

#define SCR_B   40960          // block scratch: 64 rows x 320 cols bf16 (640B rows)

// Weight image: per layer, KT tiles of [ROWS][64B] (K=32 bf16 per row, plain
// row-major k). B-frags are read DIRECTLY from L2 into registers (coalesced
// 1KB per instruction) -- no LDS staging, no ring, no barriers in K-loops.
// Edge image: L1@0 (2x20480), L2@40960 (10x20480), L3@245760 (10x20480),
//             L4@450560 (10x8192, 128 rows). Total 532480 B.
// Node image: L1@0 (4x20480), L2@81920, L3@286720, L4@491520 (10x20480 each).
#define E_L1 0
#define E_L2 40960
#define E_L3 245760
#define E_L4 450560
#define N_L1 0
#define N_L2 81920
#define N_L3 286720
#define N_L4 491520

typedef short v8s __attribute__((ext_vector_type(8)));
typedef float v4f __attribute__((ext_vector_type(4)));
typedef float f4  __attribute__((ext_vector_type(4)));

__device__ __forceinline__ short f2bf_s(float f) {
    __hip_bfloat16 h = __float2bfloat16(f);
    return *reinterpret_cast<short*>(&h);
}

// ---------------------------------------------------------------------------
// Fused MLP chain, 256 threads = 4 waves, 64 rows/block, LDS = 40KB scratch
// only -> 3 blocks/CU (launch_bounds cap), 12 waves/CU.
// Wave wc owns all 64 rows x cols [wc*80, wc*80+80). acc = 4 panels x 5 v4f.
// Per K=32 tile per wave: 5 B global_load_dwordx4 (L2-resident weights,
// register operands) + 4 A ds_read_b128 (swizzled scratch) + 20 MFMA.
// K-loops are barrier-free and explicitly software-pipelined (cur/next).
// Layer turnaround: DUMP = [barrier; swizzled scratch write; lgkmcnt(0);
// barrier]. 8 barriers per block total.
// ---------------------------------------------------------------------------
template <bool EDGE>
__global__ __launch_bounds__(256, 3)
void chain_kernel(const float* __restrict__ x, const int* __restrict__ ei,
                  const float* __restrict__ ea,
                  const float* __restrict__ aggr_in,
                  const char* __restrict__ wimg,
                  const float* __restrict__ b1, const float* __restrict__ b2,
                  const float* __restrict__ b3, const float* __restrict__ b4,
                  float* __restrict__ outp)
{
    __shared__ __align__(16) char scr[SCR_B];
    const int tid  = threadIdx.x;
    const int lane = tid & 63;
    const int wc   = tid >> 6;    // 0..3 (80-col quarter; wave owns all 64 rows)
    const int l15  = lane & 15;
    const int kk   = lane >> 4;   // 0..3 (k-chunk of 8)
    const int rowbase = blockIdx.x*64;

    v4f acc[4][5];
#pragma unroll
    for (int p = 0; p < 4; ++p)
#pragma unroll
        for (int n = 0; n < 5; ++n) acc[p][n] = (v4f){0.f,0.f,0.f,0.f};

    // ---- bias preload ----
    float bb1[5], bb2[5], bb3[5], bb4[5];
#pragma unroll
    for (int n = 0; n < 5; ++n) {
        int colb = wc*80 + n*16 + l15;
        bb1[n] = b1[colb]; bb2[n] = b2[colb]; bb3[n] = b3[colb];
        if (EDGE) bb4[n] = (n < 2) ? b4[wc*32 + n*16 + l15] : 0.f;
        else      bb4[n] = b4[colb];
    }

// B-frag from global (L2-resident weight image), coalesced: lanes (l15,kk)
// cover rows r..r+15 x full 64B k-row = contiguous 1KB per instruction.
#define BLOAD(DST, BASE, STRIDE, T, CB, NT)                                     \
    { const char* bp_ = (BASE) + (size_t)(T)*(STRIDE);                          \
      _Pragma("unroll")                                                         \
      for (int n_ = 0; n_ < (NT); ++n_)                                         \
        (DST)[n_] = *(const v8s*)(bp_ + ((CB)+n_*16+l15)*64 + kk*16); }

// A-frag from scratch: row = p*16+l15 (640B rows, 40 chunks), chunk
// (kt*4+kk) ^ (l15&7)   [proven conflict-free family]
#define ALOAD(DST, KT)                                                          \
    { _Pragma("unroll")                                                         \
      for (int p_ = 0; p_ < 4; ++p_) {                                          \
        int c_ = ((KT)*4 + kk) ^ (l15 & 7);                                     \
        (DST)[p_] = *(const v8s*)(scr + (p_*16 + l15)*640 + (c_<<4)); } }

// A-frag for node L1 straight from fp32 aggr (global), cvt in-register.
#define AGLOAD(DST, KT)                                                         \
    { _Pragma("unroll")                                                         \
      for (int p_ = 0; p_ < 4; ++p_) {                                          \
        const float* ap_ = aggr_in + (size_t)(rowbase+p_*16+l15)*128            \
                            + (KT)*32 + kk*8;                                   \
        f4 u0_ = *(const f4*)ap_, u1_ = *(const f4*)(ap_+4);                    \
        v8s t_;                                                                 \
        _Pragma("unroll")                                                       \
        for (int j_ = 0; j_ < 4; ++j_) { t_[j_] = f2bf_s(u0_[j_]);              \
                                         t_[4+j_] = f2bf_s(u1_[j_]); }          \
        (DST)[p_] = t_; } }

#define MFMA_NT(A_, B_, NT)                                                     \
    { _Pragma("unroll")                                                         \
      for (int n_ = 0; n_ < (NT); ++n_)                                         \
        _Pragma("unroll")                                                       \
        for (int p_ = 0; p_ < 4; ++p_)                                          \
          acc[p_][n_] = __builtin_amdgcn_mfma_f32_16x16x32_bf16(                \
              (A_)[p_], (B_)[n_], acc[p_][n_], 0, 0, 0); }

// Dump acc (C: col=wc*80+n*16+l15, row=p*16+kk*4+rr) -> scratch bf16,
// chunk XOR (row&7); reset acc. [barrier; write; lgkmcnt(0); barrier]
#define DUMP_RELU(BB_)                                                          \
    { __builtin_amdgcn_s_barrier();  /* all waves done reading scratch */       \
      _Pragma("unroll")                                                         \
      for (int p_ = 0; p_ < 4; ++p_)                                            \
        _Pragma("unroll")                                                       \
        for (int n_ = 0; n_ < 5; ++n_) {                                        \
          int col_ = wc*80 + n_*16 + l15;                                       \
          _Pragma("unroll")                                                     \
          for (int rr_ = 0; rr_ < 4; ++rr_) {                                   \
            int row_ = p_*16 + kk*4 + rr_;                                      \
            float v_ = fmaxf(acc[p_][n_][rr_] + (BB_)[n_], 0.f);                \
            *(__hip_bfloat16*)(scr + row_*640 +                                 \
                (((col_>>3) ^ (row_&7))<<4) + (col_&7)*2) = __float2bfloat16(v_); \
          }                                                                     \
          acc[p_][n_] = (v4f){0.f,0.f,0.f,0.f};                                 \
        }                                                                       \
      asm volatile("s_waitcnt lgkmcnt(0)" ::: "memory");                        \
      __builtin_amdgcn_s_barrier(); }

    // ================= L1 =================
    if (EDGE) {
        // A gathered in registers: af1[kt][panel], k0: [x_dst|x_src], k1: [ea|0]
        v8s af1[2][4];
#pragma unroll
        for (int p = 0; p < 4; ++p) {
            const int e = rowbase + p*16 + l15;
            const int nidx = (kk < 2) ? ei[E_TOTAL + e] : ei[e];
            const float* xs = x + (size_t)nidx*16 + (kk & 1)*8;
            f4 p0 = *(const f4*)xs, p1 = *(const f4*)(xs + 4);
            v8s a0, a1;
#pragma unroll
            for (int j = 0; j < 4; ++j) { a0[j] = f2bf_s(p0[j]); a0[4+j] = f2bf_s(p1[j]); }
            if (kk == 0) {
                const float* es = ea + (size_t)e*8;
                f4 q0 = *(const f4*)es, q1 = *(const f4*)(es + 4);
#pragma unroll
                for (int j = 0; j < 4; ++j) { a1[j] = f2bf_s(q0[j]); a1[4+j] = f2bf_s(q1[j]); }
            } else {
#pragma unroll
                for (int j = 0; j < 8; ++j) a1[j] = 0;
            }
            af1[0][p] = a0; af1[1][p] = a1;
        }
        v8s Bc[5], Bn[5];
        BLOAD(Bc, wimg + E_L1, 20480, 0, wc*80, 5);
#pragma unroll
        for (int kt = 0; kt < 2; ++kt) {
            if (kt < 1) BLOAD(Bn, wimg + E_L1, 20480, kt+1, wc*80, 5);
            MFMA_NT(af1[kt], Bc, 5);
            if (kt < 1) {
#pragma unroll
                for (int q = 0; q < 5; ++q) Bc[q] = Bn[q];
            }
        }
    } else {
        v8s Ac[4], An[4], Bc[5], Bn[5];
        AGLOAD(Ac, 0);
        BLOAD(Bc, wimg + N_L1, 20480, 0, wc*80, 5);
#pragma unroll
        for (int kt = 0; kt < 4; ++kt) {
            if (kt < 3) { AGLOAD(An, kt+1); BLOAD(Bn, wimg + N_L1, 20480, kt+1, wc*80, 5); }
            MFMA_NT(Ac, Bc, 5);
            if (kt < 3) {
#pragma unroll
                for (int q = 0; q < 4; ++q) Ac[q] = An[q];
#pragma unroll
                for (int q = 0; q < 5; ++q) Bc[q] = Bn[q];
            }
        }
    }
    DUMP_RELU(bb1);

    // ================= L2 =================
    {
        const char* wb = wimg + (EDGE ? E_L2 : N_L2);
        v8s Ac[4], An[4], Bc[5], Bn[5];
        ALOAD(Ac, 0);
        BLOAD(Bc, wb, 20480, 0, wc*80, 5);
#pragma unroll
        for (int kt = 0; kt < 10; ++kt) {
            if (kt < 9) { ALOAD(An, kt+1); BLOAD(Bn, wb, 20480, kt+1, wc*80, 5); }
            MFMA_NT(Ac, Bc, 5);
            if (kt < 9) {
#pragma unroll
                for (int q = 0; q < 4; ++q) Ac[q] = An[q];
#pragma unroll
                for (int q = 0; q < 5; ++q) Bc[q] = Bn[q];
            }
        }
    }
    DUMP_RELU(bb2);

    // ================= L3 =================
    {
        const char* wb = wimg + (EDGE ? E_L3 : N_L3);
        v8s Ac[4], An[4], Bc[5], Bn[5];
        ALOAD(Ac, 0);
        BLOAD(Bc, wb, 20480, 0, wc*80, 5);
#pragma unroll
        for (int kt = 0; kt < 10; ++kt) {
            if (kt < 9) { ALOAD(An, kt+1); BLOAD(Bn, wb, 20480, kt+1, wc*80, 5); }
            MFMA_NT(Ac, Bc, 5);
            if (kt < 9) {
#pragma unroll
                for (int q = 0; q < 4; ++q) Ac[q] = An[q];
#pragma unroll
                for (int q = 0; q < 5; ++q) Bc[q] = Bn[q];
            }
        }
    }
    DUMP_RELU(bb3);

    // ================= L4 =================
    if (EDGE) {
        // msg layer N=128 (tiles are 128 rows, stride 8192) + fused scatter
        v8s Ac[4], An[4], Bc[2], Bn[2];
        ALOAD(Ac, 0);
        BLOAD(Bc, wimg + E_L4, 8192, 0, wc*32, 2);
#pragma unroll
        for (int kt = 0; kt < 10; ++kt) {
            if (kt < 9) { ALOAD(An, kt+1); BLOAD(Bn, wimg + E_L4, 8192, kt+1, wc*32, 2); }
            MFMA_NT(Ac, Bc, 2);
            if (kt < 9) {
#pragma unroll
                for (int q = 0; q < 4; ++q) Ac[q] = An[q];
#pragma unroll
                for (int q = 0; q < 2; ++q) Bc[q] = Bn[q];
            }
        }
        // scatter-add: aggr[dst[e]*128 + col] += msg
#pragma unroll
        for (int p = 0; p < 4; ++p) {
#pragma unroll
            for (int rr = 0; rr < 4; ++rr) {
                int erow = rowbase + p*16 + kk*4 + rr;
                int d = ei[E_TOTAL + erow];
                float* ag = outp + (size_t)d*128;
#pragma unroll
                for (int n = 0; n < 2; ++n) {
                    int col = wc*32 + n*16 + l15;
                    atomicAdd(ag + col, acc[p][n][rr] + bb4[n]);
                }
            }
        }
    } else {
        v8s Ac[4], An[4], Bc[5], Bn[5];
        ALOAD(Ac, 0);
        BLOAD(Bc, wimg + N_L4, 20480, 0, wc*80, 5);
#pragma unroll
        for (int kt = 0; kt < 10; ++kt) {
            if (kt < 9) { ALOAD(An, kt+1); BLOAD(Bn, wimg + N_L4, 20480, kt+1, wc*80, 5); }
            MFMA_NT(Ac, Bc, 5);
            if (kt < 9) {
#pragma unroll
                for (int q = 0; q < 4; ++q) Ac[q] = An[q];
#pragma unroll
                for (int q = 0; q < 5; ++q) Bc[q] = Bn[q];
            }
        }
        // store node fp32 [MPAD][320]
#pragma unroll
        for (int p = 0; p < 4; ++p) {
#pragma unroll
            for (int n = 0; n < 5; ++n) {
                int col = wc*80 + n*16 + l15;
#pragma unroll
                for (int rr = 0; rr < 4; ++rr) {
                    int grow = rowbase + p*16 + kk*4 + rr;
                    outp[(size_t)grow*320 + col] = acc[p][n][rr] + bb4[n];
                }
            }
        }
    }
#undef BLOAD
#undef ALOAD
#undef AGLOAD
#undef MFMA_NT
#undef DUMP_RELU
}

// ---------------------------------------------------------------------------
// Repack fp32 W [K][N] -> bf16 tile stream: KT tiles of [ROWS][64B] (row =
// out col, 32 k per row, plain row-major k -- read into registers, no swizzle)
// ---------------------------------------------------------------------------
__global__ void repack_tiles(const float* __restrict__ src, char* __restrict__ img,
                             int K, int N, int KT, int ROWS)
{
    int t = blockIdx.x*256 + threadIdx.x;
    if (t >= KT*ROWS*32) return;
    int k32  = t & 31;
    int r    = (t >> 5) % ROWS;
    int tile = t / (ROWS*32);
    int kg   = tile*32 + k32;
    float v = (r < N && kg < K) ? src[(size_t)kg*N + r] : 0.f;
    *(__hip_bfloat16*)(img + (size_t)tile*ROWS*64 + (size_t)r*64 + k32*2) =
        __float2bfloat16(v);
}

__global__ void pad_bias(const float* __restrict__ src, float* __restrict__ dst,
                         int N, int Npad)
{
    int t = blockIdx.x*256 + threadIdx.x;
    if (t < Npad) dst[t] = (t < N) ? src[t] : 0.f;
}

__global__ void graph_starts_kernel(const int* __restrict__ batch,
                                    int* __restrict__ starts)
{
    int g = threadIdx.x;
    if (g > NGRAPHS) return;
    int lo = 0, hi = NNODES;
    while (lo < hi) {
        int mid = (lo + hi) >> 1;
        if (batch[mid] < g) lo = mid + 1; else hi = mid;
    }
    starts[g] = lo;
}

// Mean pool: node fp32 [MPAD][320] (valid cols 0..299) -> pooled [64][300]
__global__ void pool_kernel(const float* __restrict__ node,
                            const int* __restrict__ starts,
                            float* __restrict__ pooled)
{
    __shared__ float red[8][32];
    int g   = blockIdx.x;
    int col = blockIdx.y*32 + (threadIdx.x & 31);
    int rl  = threadIdx.x >> 5;
    int s = starts[g], e = starts[g + 1];
    float sum = 0.f;
    if (col < 300)
        for (int i = s + rl; i < e; i += 8) sum += node[(size_t)i*320 + col];
    red[rl][threadIdx.x & 31] = sum;
    __syncthreads();
    if (rl == 0 && col < 300) {
        float tot = 0.f;
#pragma unroll
        for (int r = 0; r < 8; ++r) tot += red[r][threadIdx.x & 31];
        float cnt = (float)(e - s);
        pooled[g*300 + col] = tot / fmaxf(cnt, 1.0f);
    }
}

__global__ void final_kernel(const float* __restrict__ pooled,
                             const float* __restrict__ lw,
                             const float* __restrict__ lb,
                             float* __restrict__ out)
{
    int t = threadIdx.x;          // 512 = 64 * 8
    int g = t / NPRED, p = t % NPRED;
    float s = lb[p];
    for (int k = 0; k < 300; ++k)
        s = fmaf(pooled[g*300 + k], lw[k*NPRED + p], s);
    out[g*NPRED + p] = s;
}

// ---------------------------------------------------------------------------
extern "C" void kernel_launch(void* const* d_in, const int* in_sizes, int n_in,
                              void* d_out, int out_size, void* d_ws, size_t ws_size,
                              hipStream_t stream)
{
    const float* x     = (const float*)d_in[0];
    const int*   ei    = (const int*)d_in[1];
    const float* ea    = (const float*)d_in[2];
    const int*   batch = (const int*)d_in[3];
    const float* mw[4] = {(const float*)d_in[4], (const float*)d_in[6],
                          (const float*)d_in[8], (const float*)d_in[10]};
    const float* mb[4] = {(const float*)d_in[5], (const float*)d_in[7],
                          (const float*)d_in[9], (const float*)d_in[11]};
    const float* nw[4] = {(const float*)d_in[12], (const float*)d_in[14],
                          (const float*)d_in[16], (const float*)d_in[18]};
    const float* nb[4] = {(const float*)d_in[13], (const float*)d_in[15],
                          (const float*)d_in[17], (const float*)d_in[19]};
    const float* lw = (const float*)d_in[20];
    const float* lb = (const float*)d_in[21];
    float* out = (float*)d_out;

    char* ws = (char*)d_ws;
    size_t off = 0;
    auto alloc = [&](size_t bytes) -> void* {
        void* p = ws + off;
        off += (bytes + 255) & ~(size_t)255;
        return p;
    };

    float* aggr   = (float*)alloc((size_t)MPAD*128*4);   // 25.6 MB
    float* node   = (float*)alloc((size_t)MPAD*320*4);   // 64.1 MB
    char*  wimg_e = (char*)alloc(532480);
    char*  wimg_n = (char*)alloc(696320);
    float* mbp[4]; float* nbp[4];
    for (int i = 0; i < 4; ++i) { mbp[i] = (float*)alloc(320*4); nbp[i] = (float*)alloc(320*4); }
    float* pooled = (float*)alloc(64*300*4);
    int*   starts = (int*)alloc(65*4);

    // ---- weight repack (transposed, K=32 tiles, plain k-major rows) ----
    auto rp = [&](const float* srcw, char* dst, int K, int N, int KT, int ROWS) {
        repack_tiles<<<(KT*ROWS*32 + 255)/256, 256, 0, stream>>>(srcw, dst, K, N, KT, ROWS);
    };
    rp(mw[0], wimg_e + E_L1,  40, 300,  2, 320);
    rp(mw[1], wimg_e + E_L2, 300, 300, 10, 320);
    rp(mw[2], wimg_e + E_L3, 300, 300, 10, 320);
    rp(mw[3], wimg_e + E_L4, 300, 128, 10, 128);
    rp(nw[0], wimg_n + N_L1, 128, 300,  4, 320);
    rp(nw[1], wimg_n + N_L2, 300, 300, 10, 320);
    rp(nw[2], wimg_n + N_L3, 300, 300, 10, 320);
    rp(nw[3], wimg_n + N_L4, 300, 300, 10, 320);
    for (int i = 0; i < 4; ++i) {
        pad_bias<<<2, 256, 0, stream>>>(mb[i], mbp[i], (i==3)?128:300, 320);
        pad_bias<<<2, 256, 0, stream>>>(nb[i], nbp[i], 300, 320);
    }
    hipMemsetAsync(aggr, 0, (size_t)MPAD*128*4, stream);
    graph_starts_kernel<<<1, 128, 0, stream>>>(batch, starts);

    // ---- edge phase: message MLP + fused scatter, all 800K edges ----
    chain_kernel<true><<<EBLK, 256, 0, stream>>>(
        x, ei, ea, nullptr, wimg_e, mbp[0], mbp[1], mbp[2], mbp[3], aggr);

    // ---- node phase (reads fp32 aggr directly) ----
    chain_kernel<false><<<NBLK, 256, 0, stream>>>(
        x, ei, ea, aggr, wimg_n, nbp[0], nbp[1], nbp[2], nbp[3], node);

    pool_kernel<<<dim3(64, 10), 256, 0, stream>>>(node, starts, pooled);
    final_kernel<<<1, 512, 0, stream>>>(pooled, lw, lb, out);
}